// Round 1
// baseline (753.471 us; speedup 1.0000x reference)
//
#include <hip/hip_runtime.h>
#include <math.h>

#define Nn 50000
#define Ee 600000
#define Bg 128      // batches (graphs)
#define Hd 128      // hidden dim
#define Kt 30       // sortpool K
#define CO 32       // conv out channels
#define KW 5        // conv kernel
#define LOUT 26     // K - KW + 1
#define CAP 2048    // per-batch node cap for topk LDS (max real count ~460)

// ---------------- init ----------------
__global__ void init_kernel(int* __restrict__ deg_i, int* __restrict__ cnt,
                            int* __restrict__ bstart) {
    int i = blockIdx.x * 256 + threadIdx.x;
    if (i < Nn) { deg_i[i] = 1; cnt[i] = 0; }   // deg starts at 1 (self loop)
    if (i <= Bg) bstart[i] = Nn;                // sentinel
}

// ---------------- degree histogram + batch starts ----------------
__global__ void count_kernel(const int* __restrict__ ei, const int* __restrict__ batch,
                             int* __restrict__ deg_i, int* __restrict__ bstart) {
    int i = blockIdx.x * 256 + threadIdx.x;
    if (i < Ee) atomicAdd(&deg_i[ei[Ee + i]], 1);       // col = edge_index[1]
    if (i < Nn) atomicMin(&bstart[batch[i]], i);
}

// ---------------- single-block scan: row_ptr, dinv, fix empty batches --------
__global__ __launch_bounds__(1024) void scan_kernel(const int* __restrict__ deg_i,
                            int* __restrict__ row_ptr, float* __restrict__ dinv,
                            int* __restrict__ bstart) {
    __shared__ int ps[1024];
    int tid = threadIdx.x;
    const int CH = 49;  // ceil(50000/1024)
    int base = tid * CH;
    int s = 0;
    for (int j = 0; j < CH; ++j) {
        int i = base + j;
        if (i < Nn) s += deg_i[i] - 1;
    }
    ps[tid] = s;
    __syncthreads();
    for (int off = 1; off < 1024; off <<= 1) {
        int v = (tid >= off) ? ps[tid - off] : 0;
        __syncthreads();
        ps[tid] += v;
        __syncthreads();
    }
    int run = (tid > 0) ? ps[tid - 1] : 0;   // exclusive prefix
    if (tid == 0) row_ptr[0] = 0;
    for (int j = 0; j < CH; ++j) {
        int i = base + j;
        if (i < Nn) {
            int d = deg_i[i];
            run += d - 1;
            row_ptr[i + 1] = run;
            dinv[i] = 1.0f / sqrtf((float)d);
        }
    }
    if (tid == 1023) {  // empty batches inherit next start (batch array sorted)
        for (int b = Bg - 1; b >= 0; --b)
            if (bstart[b] == Nn) bstart[b] = bstart[b + 1];
    }
}

// ---------------- CSR fill (edges grouped by destination col) ----------------
__global__ void fill_kernel(const int* __restrict__ ei, const int* __restrict__ row_ptr,
                            int* __restrict__ cnt, int* __restrict__ csr_src) {
    int e = blockIdx.x * 256 + threadIdx.x;
    if (e >= Ee) return;
    int c = ei[Ee + e];
    int r = ei[e];
    int p = row_ptr[c] + atomicAdd(&cnt[c], 1);
    csr_src[p] = r;
}

// ---------------- matmul: hw[i] = dinv[i] * (Hin[i] @ W) ----------------
// block: 256 thr, tile 64 rows x 128 cols, each thread 8 rows x 4 cols
#define MMR 64
__global__ __launch_bounds__(256) void mm_kernel(const float* __restrict__ Hin,
                            const float* __restrict__ W, const float* __restrict__ dinv,
                            float* __restrict__ hw) {
    __shared__ float hl[MMR * Hd];
    int row0 = blockIdx.x * MMR;
    int tid = threadIdx.x;
    // stage 64x128 row tile (float4 coalesced)
    for (int i = tid; i < MMR * Hd / 4; i += 256) {
        int r = i >> 5;          // /32 float4 per row
        int gr = row0 + r;
        float4 v = make_float4(0.f, 0.f, 0.f, 0.f);
        if (gr < Nn) v = ((const float4*)(Hin + (size_t)gr * Hd))[i & 31];
        ((float4*)hl)[i] = v;
    }
    __syncthreads();
    int cg = tid & 31;   // cols cg*4 .. cg*4+3
    int rg = tid >> 5;   // rows rg*8 .. rg*8+7
    float acc[8][4];
#pragma unroll
    for (int i = 0; i < 8; ++i)
#pragma unroll
        for (int j = 0; j < 4; ++j) acc[i][j] = 0.f;

    const float* hb = hl + rg * 8 * Hd;
#pragma unroll 4
    for (int k = 0; k < Hd; ++k) {
        float4 w = *(const float4*)(W + k * Hd + cg * 4);
#pragma unroll
        for (int i = 0; i < 8; ++i) {
            float hv = hb[i * Hd + k];
            acc[i][0] = fmaf(hv, w.x, acc[i][0]);
            acc[i][1] = fmaf(hv, w.y, acc[i][1]);
            acc[i][2] = fmaf(hv, w.z, acc[i][2]);
            acc[i][3] = fmaf(hv, w.w, acc[i][3]);
        }
    }
#pragma unroll
    for (int i = 0; i < 8; ++i) {
        int r = row0 + rg * 8 + i;
        if (r < Nn) {
            float s = dinv[r];
            float4 o = make_float4(acc[i][0] * s, acc[i][1] * s, acc[i][2] * s, acc[i][3] * s);
            *(float4*)(hw + (size_t)r * Hd + cg * 4) = o;
        }
    }
}

// ---------------- aggregation: h[i] = relu(dinv[i]*(hw[i] + sum_src hw[src]) + b) ----
// one wave per node, float2 per lane (128 feats / 64 lanes)
__global__ __launch_bounds__(256) void agg_kernel(const float* __restrict__ hw,
                            const int* __restrict__ row_ptr, const int* __restrict__ csr_src,
                            const float* __restrict__ dinv, const float* __restrict__ bias,
                            float* __restrict__ hout) {
    int node = blockIdx.x * 4 + (threadIdx.x >> 6);
    if (node >= Nn) return;
    int lane = threadIdx.x & 63;
    const float2* hw2 = (const float2*)hw;
    float2 acc = hw2[(size_t)node * 64 + lane];     // self loop term (hw pre-scaled by dinv[src])
    int e0 = row_ptr[node], e1 = row_ptr[node + 1];
    int e = e0;
    for (; e + 1 < e1; e += 2) {
        int s0 = csr_src[e], s1 = csr_src[e + 1];
        float2 v0 = hw2[(size_t)s0 * 64 + lane];
        float2 v1 = hw2[(size_t)s1 * 64 + lane];
        acc.x += v0.x + v1.x;
        acc.y += v0.y + v1.y;
    }
    if (e < e1) {
        int s0 = csr_src[e];
        float2 v0 = hw2[(size_t)s0 * 64 + lane];
        acc.x += v0.x;
        acc.y += v0.y;
    }
    float d = dinv[node];
    float2 bv = ((const float2*)bias)[lane];
    float2 o;
    o.x = fmaxf(fmaf(d, acc.x, bv.x), 0.f);
    o.y = fmaxf(fmaf(d, acc.y, bv.y), 0.f);
    ((float2*)hout)[(size_t)node * 64 + lane] = o;
}

// ---------------- top-K per batch (descending last feature, tie: smaller idx) ----
__global__ __launch_bounds__(256) void topk_kernel(const float* __restrict__ h,
                            const int* __restrict__ bstart, int* __restrict__ sel) {
    __shared__ float vals[CAP];
    __shared__ float rv[4];
    __shared__ int ri[4];
    int b = blockIdx.x, tid = threadIdx.x;
    int s0 = bstart[b], s1 = bstart[b + 1];
    int n = s1 - s0;
    int nc = n < CAP ? n : CAP;
    for (int j = tid; j < nc; j += 256)
        vals[j] = h[(size_t)(s0 + j) * Hd + (Hd - 1)];
    __syncthreads();
    for (int k = 0; k < Kt; ++k) {
        float bv = -1.f;
        int bi = 0x7fffffff;
        for (int j = tid; j < nc; j += 256) {
            float v = vals[j];
            if (v > bv || (v == bv && j < bi)) { bv = v; bi = j; }
        }
        // wave reduce (64 lanes)
        for (int off = 32; off > 0; off >>= 1) {
            float ov = __shfl_down(bv, off);
            int oi = __shfl_down(bi, off);
            if (ov > bv || (ov == bv && oi < bi)) { bv = ov; bi = oi; }
        }
        int wid = tid >> 6;
        if ((tid & 63) == 0) { rv[wid] = bv; ri[wid] = bi; }
        __syncthreads();
        if (tid == 0) {
            float fv = rv[0]; int fi = ri[0];
            for (int w = 1; w < 4; ++w) {
                if (rv[w] > fv || (rv[w] == fv && ri[w] < fi)) { fv = rv[w]; fi = ri[w]; }
            }
            if (k < n) {
                sel[b * Kt + k] = s0 + fi;
                vals[fi] = -1.f;   // relu output >= 0, so -1 can never win again
            } else {
                sel[b * Kt + k] = -1;
            }
        }
        __syncthreads();
    }
}

// ---------------- fused head: conv1d + relu + lin1 + relu + lin2 ----------------
__global__ __launch_bounds__(256) void head_kernel(const float* __restrict__ h,
                            const int* __restrict__ sel,
                            const float* __restrict__ conv_w, const float* __restrict__ conv_b,
                            const float* __restrict__ l1w, const float* __restrict__ l1b,
                            const float* __restrict__ l2w, const float* __restrict__ l2b,
                            float* __restrict__ out) {
    __shared__ float xc[Kt][Hd + 1];   // pooled, padded (+1) to avoid bank conflicts
    __shared__ float flat[CO * LOUT];  // 832
    __shared__ float z[Hd];
    __shared__ int sl[Kt];
    int b = blockIdx.x, tid = threadIdx.x;
    if (tid < Kt) sl[tid] = sel[b * Kt + tid];
    __syncthreads();
    for (int i = tid; i < Kt * Hd; i += 256) {
        int t = i >> 7, c = i & 127;
        int s = sl[t];
        xc[t][c] = (s >= 0) ? h[(size_t)s * Hd + c] : 0.f;
    }
    __syncthreads();
    // conv: flat[o*26+t] = relu(b[o] + sum_ci sum_k xc[t+k][ci]*w[o][ci][k])
    for (int oi = tid; oi < CO * LOUT; oi += 256) {
        int o = oi / LOUT, t = oi - o * LOUT;
        float acc = conv_b[o];
        const float* wp = conv_w + o * (Hd * KW);
        for (int ci = 0; ci < Hd; ++ci) {
#pragma unroll
            for (int k = 0; k < KW; ++k)
                acc = fmaf(xc[t + k][ci], wp[ci * KW + k], acc);
        }
        flat[oi] = fmaxf(acc, 0.f);
    }
    __syncthreads();
    if (tid < Hd) {
        float acc = l1b[tid];
        for (int m = 0; m < CO * LOUT; ++m)
            acc = fmaf(flat[m], l1w[m * Hd + tid], acc);
        z[tid] = fmaxf(acc, 0.f);
    }
    __syncthreads();
    if (tid < 10) {
        float acc = l2b[tid];
        for (int j = 0; j < Hd; ++j)
            acc = fmaf(z[j], l2w[j * 10 + tid], acc);
        out[b * 10 + tid] = acc;
    }
}

extern "C" void kernel_launch(void* const* d_in, const int* in_sizes, int n_in,
                              void* d_out, int out_size, void* d_ws, size_t ws_size,
                              hipStream_t stream) {
    const float* x      = (const float*)d_in[0];
    const int*   ei     = (const int*)d_in[1];
    const int*   batch  = (const int*)d_in[2];
    const float* W0     = (const float*)d_in[3];
    const float* b0     = (const float*)d_in[4];
    const float* W1     = (const float*)d_in[5];
    const float* b1     = (const float*)d_in[6];
    const float* W2     = (const float*)d_in[7];
    const float* b2     = (const float*)d_in[8];
    const float* conv_w = (const float*)d_in[9];
    const float* conv_b = (const float*)d_in[10];
    const float* l1w    = (const float*)d_in[11];
    const float* l1b    = (const float*)d_in[12];
    const float* l2w    = (const float*)d_in[13];
    const float* l2b    = (const float*)d_in[14];
    float* out = (float*)d_out;

    // workspace layout (ints/floats are 4B; hw/hbuf kept 16B aligned)
    int* wsI = (int*)d_ws;
    size_t off = 0;
    int*   deg_i   = wsI + off; off += Nn;
    int*   cnt     = wsI + off; off += Nn;
    int*   row_ptr = wsI + off; off += 50004;      // N+1 padded
    int*   bstart  = wsI + off; off += 132;        // B+1 padded
    float* dinv    = (float*)(wsI + off); off += Nn;
    int*   sel     = wsI + off; off += Bg * Kt + 16;
    int*   csr_src = wsI + off; off += Ee;
    // align to 16B
    off = (off + 3) & ~(size_t)3;
    float* hw   = (float*)(wsI + off); off += (size_t)Nn * Hd;
    float* hbuf = (float*)(wsI + off); off += (size_t)Nn * Hd;

    // 1. init
    init_kernel<<<(Nn + 255) / 256, 256, 0, stream>>>(deg_i, cnt, bstart);
    // 2. degree histogram + batch starts
    count_kernel<<<(Ee + 255) / 256, 256, 0, stream>>>(ei, batch, deg_i, bstart);
    // 3. scan -> row_ptr, dinv, bstart fix
    scan_kernel<<<1, 1024, 0, stream>>>(deg_i, row_ptr, dinv, bstart);
    // 4. CSR fill
    fill_kernel<<<(Ee + 255) / 256, 256, 0, stream>>>(ei, row_ptr, cnt, csr_src);

    // 5. three GCN layers
    dim3 mmGrid((Nn + MMR - 1) / MMR);
    dim3 aggGrid((Nn + 3) / 4);
    mm_kernel<<<mmGrid, 256, 0, stream>>>(x, W0, dinv, hw);
    agg_kernel<<<aggGrid, 256, 0, stream>>>(hw, row_ptr, csr_src, dinv, b0, hbuf);
    mm_kernel<<<mmGrid, 256, 0, stream>>>(hbuf, W1, dinv, hw);
    agg_kernel<<<aggGrid, 256, 0, stream>>>(hw, row_ptr, csr_src, dinv, b1, hbuf);
    mm_kernel<<<mmGrid, 256, 0, stream>>>(hbuf, W2, dinv, hw);
    agg_kernel<<<aggGrid, 256, 0, stream>>>(hw, row_ptr, csr_src, dinv, b2, hbuf);

    // 6. sort-pool top-K per batch
    topk_kernel<<<Bg, 256, 0, stream>>>(hbuf, bstart, sel);
    // 7. fused conv + fc head
    head_kernel<<<Bg, 256, 0, stream>>>(hbuf, sel, conv_w, conv_b, l1w, l1b, l2w, l2b, out);
}

// Round 2
// 638.141 us; speedup vs baseline: 1.1807x; 1.1807x over previous
//
#include <hip/hip_runtime.h>
#include <math.h>

#define Nn 50000
#define Ee 600000
#define Bg 128      // batches (graphs)
#define Hd 128      // hidden dim
#define Kt 30       // sortpool K
#define CO 32       // conv out channels
#define KW 5        // conv kernel
#define LOUT 26     // K - KW + 1
#define CAP 2048    // per-batch node cap for topk LDS (max real count ~460)

// ---------------- init ----------------
__global__ void init_kernel(int* __restrict__ deg_i, int* __restrict__ cnt,
                            int* __restrict__ bstart) {
    int i = blockIdx.x * 256 + threadIdx.x;
    if (i < Nn) { deg_i[i] = 1; cnt[i] = 0; }   // deg starts at 1 (self loop)
    if (i <= Bg) bstart[i] = Nn;                // sentinel
}

// ---------------- degree histogram + batch starts (boundary detect, NO atomics on bstart) ----
__global__ void count_kernel(const int* __restrict__ ei, const int* __restrict__ batch,
                             int* __restrict__ deg_i, int* __restrict__ bstart) {
    int i = blockIdx.x * 256 + threadIdx.x;
    if (i < Ee) atomicAdd(&deg_i[ei[Ee + i]], 1);       // col = edge_index[1]
    if (i < Nn) {
        // batch is sorted: node i starts batch b iff i==0 or batch[i-1]!=batch[i]
        int b = batch[i];
        if (i == 0) {
            bstart[b] = 0;
        } else {
            int bp = batch[i - 1];
            if (bp != b) bstart[b] = i;
        }
    }
}

// ---------------- single-block scan: row_ptr, dinv, fix empty batches --------
__global__ __launch_bounds__(1024) void scan_kernel(const int* __restrict__ deg_i,
                            int* __restrict__ row_ptr, float* __restrict__ dinv,
                            int* __restrict__ bstart) {
    __shared__ int ps[1024];
    int tid = threadIdx.x;
    const int CH = 49;  // ceil(50000/1024)
    int base = tid * CH;
    int s = 0;
    for (int j = 0; j < CH; ++j) {
        int i = base + j;
        if (i < Nn) s += deg_i[i] - 1;
    }
    ps[tid] = s;
    __syncthreads();
    for (int off = 1; off < 1024; off <<= 1) {
        int v = (tid >= off) ? ps[tid - off] : 0;
        __syncthreads();
        ps[tid] += v;
        __syncthreads();
    }
    int run = (tid > 0) ? ps[tid - 1] : 0;   // exclusive prefix
    if (tid == 0) row_ptr[0] = 0;
    for (int j = 0; j < CH; ++j) {
        int i = base + j;
        if (i < Nn) {
            int d = deg_i[i];
            run += d - 1;
            row_ptr[i + 1] = run;
            dinv[i] = 1.0f / sqrtf((float)d);
        }
    }
    if (tid == 1023) {  // empty batches inherit next start (batch array sorted)
        for (int b = Bg - 1; b >= 0; --b)
            if (bstart[b] == Nn) bstart[b] = bstart[b + 1];
    }
}

// ---------------- CSR fill (edges grouped by destination col) ----------------
__global__ void fill_kernel(const int* __restrict__ ei, const int* __restrict__ row_ptr,
                            int* __restrict__ cnt, int* __restrict__ csr_src) {
    int e = blockIdx.x * 256 + threadIdx.x;
    if (e >= Ee) return;
    int c = ei[Ee + e];
    int r = ei[e];
    int p = row_ptr[c] + atomicAdd(&cnt[c], 1);
    csr_src[p] = r;
}

// ---------------- matmul: hw[i] = dinv[i] * (Hin[i] @ W) ----------------
// block: 256 thr, tile 64 rows x 128 cols, each thread 8 rows x 4 cols
#define MMR 64
__global__ __launch_bounds__(256) void mm_kernel(const float* __restrict__ Hin,
                            const float* __restrict__ W, const float* __restrict__ dinv,
                            float* __restrict__ hw) {
    __shared__ float hl[MMR * Hd];
    int row0 = blockIdx.x * MMR;
    int tid = threadIdx.x;
    // stage 64x128 row tile (float4 coalesced)
    for (int i = tid; i < MMR * Hd / 4; i += 256) {
        int r = i >> 5;          // /32 float4 per row
        int gr = row0 + r;
        float4 v = make_float4(0.f, 0.f, 0.f, 0.f);
        if (gr < Nn) v = ((const float4*)(Hin + (size_t)gr * Hd))[i & 31];
        ((float4*)hl)[i] = v;
    }
    __syncthreads();
    int cg = tid & 31;   // cols cg*4 .. cg*4+3
    int rg = tid >> 5;   // rows rg*8 .. rg*8+7
    float acc[8][4];
#pragma unroll
    for (int i = 0; i < 8; ++i)
#pragma unroll
        for (int j = 0; j < 4; ++j) acc[i][j] = 0.f;

    const float* hb = hl + rg * 8 * Hd;
#pragma unroll 4
    for (int k = 0; k < Hd; ++k) {
        float4 w = *(const float4*)(W + k * Hd + cg * 4);
#pragma unroll
        for (int i = 0; i < 8; ++i) {
            float hv = hb[i * Hd + k];
            acc[i][0] = fmaf(hv, w.x, acc[i][0]);
            acc[i][1] = fmaf(hv, w.y, acc[i][1]);
            acc[i][2] = fmaf(hv, w.z, acc[i][2]);
            acc[i][3] = fmaf(hv, w.w, acc[i][3]);
        }
    }
#pragma unroll
    for (int i = 0; i < 8; ++i) {
        int r = row0 + rg * 8 + i;
        if (r < Nn) {
            float s = dinv[r];
            float4 o = make_float4(acc[i][0] * s, acc[i][1] * s, acc[i][2] * s, acc[i][3] * s);
            *(float4*)(hw + (size_t)r * Hd + cg * 4) = o;
        }
    }
}

// ---------------- aggregation: h[i] = relu(dinv[i]*(hw[i] + sum_src hw[src]) + b) ----
// one wave per node, float2 per lane (128 feats / 64 lanes)
__global__ __launch_bounds__(256) void agg_kernel(const float* __restrict__ hw,
                            const int* __restrict__ row_ptr, const int* __restrict__ csr_src,
                            const float* __restrict__ dinv, const float* __restrict__ bias,
                            float* __restrict__ hout) {
    int node = blockIdx.x * 4 + (threadIdx.x >> 6);
    if (node >= Nn) return;
    int lane = threadIdx.x & 63;
    const float2* hw2 = (const float2*)hw;
    float2 acc = hw2[(size_t)node * 64 + lane];     // self loop term (hw pre-scaled by dinv[src])
    int e0 = row_ptr[node], e1 = row_ptr[node + 1];
    int e = e0;
    for (; e + 1 < e1; e += 2) {
        int s0 = csr_src[e], s1 = csr_src[e + 1];
        float2 v0 = hw2[(size_t)s0 * 64 + lane];
        float2 v1 = hw2[(size_t)s1 * 64 + lane];
        acc.x += v0.x + v1.x;
        acc.y += v0.y + v1.y;
    }
    if (e < e1) {
        int s0 = csr_src[e];
        float2 v0 = hw2[(size_t)s0 * 64 + lane];
        acc.x += v0.x;
        acc.y += v0.y;
    }
    float d = dinv[node];
    float2 bv = ((const float2*)bias)[lane];
    float2 o;
    o.x = fmaxf(fmaf(d, acc.x, bv.x), 0.f);
    o.y = fmaxf(fmaf(d, acc.y, bv.y), 0.f);
    ((float2*)hout)[(size_t)node * 64 + lane] = o;
}

// ---------------- top-K per batch (descending last feature, tie: smaller idx) ----
__global__ __launch_bounds__(256) void topk_kernel(const float* __restrict__ h,
                            const int* __restrict__ bstart, int* __restrict__ sel) {
    __shared__ float vals[CAP];
    __shared__ float rv[4];
    __shared__ int ri[4];
    int b = blockIdx.x, tid = threadIdx.x;
    int s0 = bstart[b], s1 = bstart[b + 1];
    int n = s1 - s0;
    int nc = n < CAP ? n : CAP;
    for (int j = tid; j < nc; j += 256)
        vals[j] = h[(size_t)(s0 + j) * Hd + (Hd - 1)];
    __syncthreads();
    for (int k = 0; k < Kt; ++k) {
        float bv = -1.f;
        int bi = 0x7fffffff;
        for (int j = tid; j < nc; j += 256) {
            float v = vals[j];
            if (v > bv || (v == bv && j < bi)) { bv = v; bi = j; }
        }
        // wave reduce (64 lanes)
        for (int off = 32; off > 0; off >>= 1) {
            float ov = __shfl_down(bv, off);
            int oi = __shfl_down(bi, off);
            if (ov > bv || (ov == bv && oi < bi)) { bv = ov; bi = oi; }
        }
        int wid = tid >> 6;
        if ((tid & 63) == 0) { rv[wid] = bv; ri[wid] = bi; }
        __syncthreads();
        if (tid == 0) {
            float fv = rv[0]; int fi = ri[0];
            for (int w = 1; w < 4; ++w) {
                if (rv[w] > fv || (rv[w] == fv && ri[w] < fi)) { fv = rv[w]; fi = ri[w]; }
            }
            if (k < n) {
                sel[b * Kt + k] = s0 + fi;
                vals[fi] = -1.f;   // relu output >= 0, so -1 can never win again
            } else {
                sel[b * Kt + k] = -1;
            }
        }
        __syncthreads();
    }
}

// ---------------- fused head: conv1d + relu + lin1 + relu + lin2 ----------------
__global__ __launch_bounds__(256) void head_kernel(const float* __restrict__ h,
                            const int* __restrict__ sel,
                            const float* __restrict__ conv_w, const float* __restrict__ conv_b,
                            const float* __restrict__ l1w, const float* __restrict__ l1b,
                            const float* __restrict__ l2w, const float* __restrict__ l2b,
                            float* __restrict__ out) {
    __shared__ float xc[Kt][Hd + 1];   // pooled, padded (+1) to avoid bank conflicts
    __shared__ float flat[CO * LOUT];  // 832
    __shared__ float z[Hd];
    __shared__ int sl[Kt];
    int b = blockIdx.x, tid = threadIdx.x;
    if (tid < Kt) sl[tid] = sel[b * Kt + tid];
    __syncthreads();
    for (int i = tid; i < Kt * Hd; i += 256) {
        int t = i >> 7, c = i & 127;
        int s = sl[t];
        xc[t][c] = (s >= 0) ? h[(size_t)s * Hd + c] : 0.f;
    }
    __syncthreads();
    // conv: flat[o*26+t] = relu(b[o] + sum_ci sum_k xc[t+k][ci]*w[o][ci][k])
    for (int oi = tid; oi < CO * LOUT; oi += 256) {
        int o = oi / LOUT, t = oi - o * LOUT;
        float acc = conv_b[o];
        const float* wp = conv_w + o * (Hd * KW);
        for (int ci = 0; ci < Hd; ++ci) {
#pragma unroll
            for (int k = 0; k < KW; ++k)
                acc = fmaf(xc[t + k][ci], wp[ci * KW + k], acc);
        }
        flat[oi] = fmaxf(acc, 0.f);
    }
    __syncthreads();
    if (tid < Hd) {
        float acc = l1b[tid];
        for (int m = 0; m < CO * LOUT; ++m)
            acc = fmaf(flat[m], l1w[m * Hd + tid], acc);
        z[tid] = fmaxf(acc, 0.f);
    }
    __syncthreads();
    if (tid < 10) {
        float acc = l2b[tid];
        for (int j = 0; j < Hd; ++j)
            acc = fmaf(z[j], l2w[j * 10 + tid], acc);
        out[b * 10 + tid] = acc;
    }
}

extern "C" void kernel_launch(void* const* d_in, const int* in_sizes, int n_in,
                              void* d_out, int out_size, void* d_ws, size_t ws_size,
                              hipStream_t stream) {
    const float* x      = (const float*)d_in[0];
    const int*   ei     = (const int*)d_in[1];
    const int*   batch  = (const int*)d_in[2];
    const float* W0     = (const float*)d_in[3];
    const float* b0     = (const float*)d_in[4];
    const float* W1     = (const float*)d_in[5];
    const float* b1     = (const float*)d_in[6];
    const float* W2     = (const float*)d_in[7];
    const float* b2     = (const float*)d_in[8];
    const float* conv_w = (const float*)d_in[9];
    const float* conv_b = (const float*)d_in[10];
    const float* l1w    = (const float*)d_in[11];
    const float* l1b    = (const float*)d_in[12];
    const float* l2w    = (const float*)d_in[13];
    const float* l2b    = (const float*)d_in[14];
    float* out = (float*)d_out;

    // workspace layout (ints/floats are 4B; hw/hbuf kept 16B aligned)
    int* wsI = (int*)d_ws;
    size_t off = 0;
    int*   deg_i   = wsI + off; off += Nn;
    int*   cnt     = wsI + off; off += Nn;
    int*   row_ptr = wsI + off; off += 50004;      // N+1 padded
    int*   bstart  = wsI + off; off += 132;        // B+1 padded
    float* dinv    = (float*)(wsI + off); off += Nn;
    int*   sel     = wsI + off; off += Bg * Kt + 16;
    int*   csr_src = wsI + off; off += Ee;
    // align to 16B
    off = (off + 3) & ~(size_t)3;
    float* hw   = (float*)(wsI + off); off += (size_t)Nn * Hd;
    float* hbuf = (float*)(wsI + off); off += (size_t)Nn * Hd;

    // 1. init
    init_kernel<<<(Nn + 255) / 256, 256, 0, stream>>>(deg_i, cnt, bstart);
    // 2. degree histogram + batch starts (boundary detect)
    count_kernel<<<(Ee + 255) / 256, 256, 0, stream>>>(ei, batch, deg_i, bstart);
    // 3. scan -> row_ptr, dinv, bstart fix
    scan_kernel<<<1, 1024, 0, stream>>>(deg_i, row_ptr, dinv, bstart);
    // 4. CSR fill
    fill_kernel<<<(Ee + 255) / 256, 256, 0, stream>>>(ei, row_ptr, cnt, csr_src);

    // 5. three GCN layers
    dim3 mmGrid((Nn + MMR - 1) / MMR);
    dim3 aggGrid((Nn + 3) / 4);
    mm_kernel<<<mmGrid, 256, 0, stream>>>(x, W0, dinv, hw);
    agg_kernel<<<aggGrid, 256, 0, stream>>>(hw, row_ptr, csr_src, dinv, b0, hbuf);
    mm_kernel<<<mmGrid, 256, 0, stream>>>(hbuf, W1, dinv, hw);
    agg_kernel<<<aggGrid, 256, 0, stream>>>(hw, row_ptr, csr_src, dinv, b1, hbuf);
    mm_kernel<<<mmGrid, 256, 0, stream>>>(hbuf, W2, dinv, hw);
    agg_kernel<<<aggGrid, 256, 0, stream>>>(hw, row_ptr, csr_src, dinv, b2, hbuf);

    // 6. sort-pool top-K per batch
    topk_kernel<<<Bg, 256, 0, stream>>>(hbuf, bstart, sel);
    // 7. fused conv + fc head
    head_kernel<<<Bg, 256, 0, stream>>>(hbuf, sel, conv_w, conv_b, l1w, l1b, l2w, l2b, out);
}

// Round 3
// 526.444 us; speedup vs baseline: 1.4312x; 1.2122x over previous
//
#include <hip/hip_runtime.h>
#include <math.h>

#define Nn 50000
#define Ee 600000
#define Bg 128      // batches (graphs)
#define Hd 128      // hidden dim
#define Kt 30       // sortpool K
#define CO 32       // conv out channels
#define KW 5        // conv kernel
#define LOUT 26     // K - KW + 1
#define CAP 2048    // per-batch node cap for topk LDS (max real count ~460)
#define SCB 196     // ceil(50000/256) scan blocks

// ---------------- init ----------------
__global__ void init_kernel(int* __restrict__ deg_i, int* __restrict__ cnt,
                            int* __restrict__ bstart) {
    int i = blockIdx.x * 256 + threadIdx.x;
    if (i < Nn) { deg_i[i] = 1; cnt[i] = 0; }   // deg starts at 1 (self loop)
    if (i <= Bg) bstart[i] = Nn;                // sentinel
}

// ---------------- degree histogram + batch starts (boundary detect) ----------
__global__ void count_kernel(const int* __restrict__ ei, const int* __restrict__ batch,
                             int* __restrict__ deg_i, int* __restrict__ bstart) {
    int i = blockIdx.x * 256 + threadIdx.x;
    if (i < Ee) atomicAdd(&deg_i[ei[Ee + i]], 1);       // col = edge_index[1]
    if (i < Nn) {
        // batch is sorted: node i starts batch b iff i==0 or batch[i-1]!=batch[i]
        int b = batch[i];
        if (i == 0) {
            bstart[b] = 0;
        } else {
            int bp = batch[i - 1];
            if (bp != b) bstart[b] = i;
        }
    }
}

// ---------------- scan phase A: block sums of (deg-1), dinv ----------------
__global__ __launch_bounds__(256) void scanA_kernel(const int* __restrict__ deg_i,
                            float* __restrict__ dinv, int* __restrict__ bsum) {
    __shared__ int s[256];
    int tid = threadIdx.x;
    int i = blockIdx.x * 256 + tid;
    int v = 0;
    if (i < Nn) {
        int d = deg_i[i];
        dinv[i] = 1.0f / sqrtf((float)d);
        v = d - 1;
    }
    s[tid] = v;
    __syncthreads();
    for (int off = 128; off > 0; off >>= 1) {
        if (tid < off) s[tid] += s[tid + off];
        __syncthreads();
    }
    if (tid == 0) bsum[blockIdx.x] = s[0];
}

// ---------------- scan phase B: scan block sums; fix empty batches ----------
__global__ __launch_bounds__(256) void scanB_kernel(const int* __restrict__ bsum,
                            int* __restrict__ boff, int* __restrict__ bstart) {
    __shared__ int s[256];
    int tid = threadIdx.x;
    int v = (tid < SCB) ? bsum[tid] : 0;
    s[tid] = v;
    __syncthreads();
    for (int off = 1; off < 256; off <<= 1) {
        int t = (tid >= off) ? s[tid - off] : 0;
        __syncthreads();
        s[tid] += t;
        __syncthreads();
    }
    if (tid < SCB) boff[tid] = s[tid] - v;   // exclusive
    if (tid == 0) {   // empty batches inherit next start (batch array sorted)
        for (int b = Bg - 1; b >= 0; --b)
            if (bstart[b] == Nn) bstart[b] = bstart[b + 1];
    }
}

// ---------------- scan phase C: row_ptr = offset + local inclusive scan -----
__global__ __launch_bounds__(256) void scanC_kernel(const int* __restrict__ deg_i,
                            const int* __restrict__ boff, int* __restrict__ row_ptr) {
    __shared__ int s[256];
    int tid = threadIdx.x;
    int i = blockIdx.x * 256 + tid;
    int v = (i < Nn) ? deg_i[i] - 1 : 0;
    s[tid] = v;
    __syncthreads();
    for (int off = 1; off < 256; off <<= 1) {
        int t = (tid >= off) ? s[tid - off] : 0;
        __syncthreads();
        s[tid] += t;
        __syncthreads();
    }
    if (i < Nn) row_ptr[i + 1] = s[tid] + boff[blockIdx.x];
    if (i == 0) row_ptr[0] = 0;
}

// ---------------- CSR fill (edges grouped by destination col) ----------------
__global__ void fill_kernel(const int* __restrict__ ei, const int* __restrict__ row_ptr,
                            int* __restrict__ cnt, int* __restrict__ csr_src) {
    int e = blockIdx.x * 256 + threadIdx.x;
    if (e >= Ee) return;
    int c = ei[Ee + e];
    int r = ei[e];
    int p = row_ptr[c] + atomicAdd(&cnt[c], 1);
    csr_src[p] = r;
}

// ---------------- matmul: hw[i] = dinv[i] * (Hin[i] @ W) ----------------
// block: 256 thr, tile 64 rows x 128 cols, each thread 8 rows x 4 cols
#define MMR 64
__global__ __launch_bounds__(256) void mm_kernel(const float* __restrict__ Hin,
                            const float* __restrict__ W, const float* __restrict__ dinv,
                            float* __restrict__ hw) {
    __shared__ float hl[MMR * Hd];
    int row0 = blockIdx.x * MMR;
    int tid = threadIdx.x;
    // stage 64x128 row tile (float4 coalesced)
    for (int i = tid; i < MMR * Hd / 4; i += 256) {
        int r = i >> 5;          // /32 float4 per row
        int gr = row0 + r;
        float4 v = make_float4(0.f, 0.f, 0.f, 0.f);
        if (gr < Nn) v = ((const float4*)(Hin + (size_t)gr * Hd))[i & 31];
        ((float4*)hl)[i] = v;
    }
    __syncthreads();
    int cg = tid & 31;   // cols cg*4 .. cg*4+3
    int rg = tid >> 5;   // rows rg*8 .. rg*8+7
    float acc[8][4];
#pragma unroll
    for (int i = 0; i < 8; ++i)
#pragma unroll
        for (int j = 0; j < 4; ++j) acc[i][j] = 0.f;

    const float* hb = hl + rg * 8 * Hd;
#pragma unroll 4
    for (int k = 0; k < Hd; ++k) {
        float4 w = *(const float4*)(W + k * Hd + cg * 4);
#pragma unroll
        for (int i = 0; i < 8; ++i) {
            float hv = hb[i * Hd + k];
            acc[i][0] = fmaf(hv, w.x, acc[i][0]);
            acc[i][1] = fmaf(hv, w.y, acc[i][1]);
            acc[i][2] = fmaf(hv, w.z, acc[i][2]);
            acc[i][3] = fmaf(hv, w.w, acc[i][3]);
        }
    }
#pragma unroll
    for (int i = 0; i < 8; ++i) {
        int r = row0 + rg * 8 + i;
        if (r < Nn) {
            float s = dinv[r];
            float4 o = make_float4(acc[i][0] * s, acc[i][1] * s, acc[i][2] * s, acc[i][3] * s);
            *(float4*)(hw + (size_t)r * Hd + cg * 4) = o;
        }
    }
}

// ---------------- aggregation: h[i] = relu(dinv[i]*(hw[i] + sum_src hw[src]) + b) ----
// one wave per node, float2 per lane (128 feats / 64 lanes)
__global__ __launch_bounds__(256) void agg_kernel(const float* __restrict__ hw,
                            const int* __restrict__ row_ptr, const int* __restrict__ csr_src,
                            const float* __restrict__ dinv, const float* __restrict__ bias,
                            float* __restrict__ hout) {
    int node = blockIdx.x * 4 + (threadIdx.x >> 6);
    if (node >= Nn) return;
    int lane = threadIdx.x & 63;
    const float2* hw2 = (const float2*)hw;
    float2 acc = hw2[(size_t)node * 64 + lane];     // self loop term (hw pre-scaled by dinv[src])
    int e0 = row_ptr[node], e1 = row_ptr[node + 1];
    int e = e0;
    for (; e + 1 < e1; e += 2) {
        int s0 = csr_src[e], s1 = csr_src[e + 1];
        float2 v0 = hw2[(size_t)s0 * 64 + lane];
        float2 v1 = hw2[(size_t)s1 * 64 + lane];
        acc.x += v0.x + v1.x;
        acc.y += v0.y + v1.y;
    }
    if (e < e1) {
        int s0 = csr_src[e];
        float2 v0 = hw2[(size_t)s0 * 64 + lane];
        acc.x += v0.x;
        acc.y += v0.y;
    }
    float d = dinv[node];
    float2 bv = ((const float2*)bias)[lane];
    float2 o;
    o.x = fmaxf(fmaf(d, acc.x, bv.x), 0.f);
    o.y = fmaxf(fmaf(d, acc.y, bv.y), 0.f);
    ((float2*)hout)[(size_t)node * 64 + lane] = o;
}

// ---------------- top-K per batch (descending last feature, tie: smaller idx) ----
__global__ __launch_bounds__(256) void topk_kernel(const float* __restrict__ h,
                            const int* __restrict__ bstart, int* __restrict__ sel) {
    __shared__ float vals[CAP];
    __shared__ float rv[4];
    __shared__ int ri[4];
    int b = blockIdx.x, tid = threadIdx.x;
    int s0 = bstart[b], s1 = bstart[b + 1];
    int n = s1 - s0;
    int nc = n < CAP ? n : CAP;
    for (int j = tid; j < nc; j += 256)
        vals[j] = h[(size_t)(s0 + j) * Hd + (Hd - 1)];
    __syncthreads();
    for (int k = 0; k < Kt; ++k) {
        float bv = -1.f;
        int bi = 0x7fffffff;
        for (int j = tid; j < nc; j += 256) {
            float v = vals[j];
            if (v > bv || (v == bv && j < bi)) { bv = v; bi = j; }
        }
        // wave reduce (64 lanes)
        for (int off = 32; off > 0; off >>= 1) {
            float ov = __shfl_down(bv, off);
            int oi = __shfl_down(bi, off);
            if (ov > bv || (ov == bv && oi < bi)) { bv = ov; bi = oi; }
        }
        int wid = tid >> 6;
        if ((tid & 63) == 0) { rv[wid] = bv; ri[wid] = bi; }
        __syncthreads();
        if (tid == 0) {
            float fv = rv[0]; int fi = ri[0];
            for (int w = 1; w < 4; ++w) {
                if (rv[w] > fv || (rv[w] == fv && ri[w] < fi)) { fv = rv[w]; fi = ri[w]; }
            }
            if (k < n) {
                sel[b * Kt + k] = s0 + fi;
                vals[fi] = -1.f;   // relu output >= 0, so -1 can never win again
            } else {
                sel[b * Kt + k] = -1;
            }
        }
        __syncthreads();
    }
}

// ---------------- fused head: conv1d + relu + lin1 + relu + lin2 ----------------
__global__ __launch_bounds__(256) void head_kernel(const float* __restrict__ h,
                            const int* __restrict__ sel,
                            const float* __restrict__ conv_w, const float* __restrict__ conv_b,
                            const float* __restrict__ l1w, const float* __restrict__ l1b,
                            const float* __restrict__ l2w, const float* __restrict__ l2b,
                            float* __restrict__ out) {
    __shared__ float xc[Kt][Hd + 1];   // pooled, padded (+1) to avoid bank conflicts
    __shared__ float flat[CO * LOUT];  // 832
    __shared__ float z[Hd];
    __shared__ int sl[Kt];
    int b = blockIdx.x, tid = threadIdx.x;
    if (tid < Kt) sl[tid] = sel[b * Kt + tid];
    __syncthreads();
    for (int i = tid; i < Kt * Hd; i += 256) {
        int t = i >> 7, c = i & 127;
        int s = sl[t];
        xc[t][c] = (s >= 0) ? h[(size_t)s * Hd + c] : 0.f;
    }
    __syncthreads();
    // conv: flat[o*26+t] = relu(b[o] + sum_ci sum_k xc[t+k][ci]*w[o][ci][k])
    for (int oi = tid; oi < CO * LOUT; oi += 256) {
        int o = oi / LOUT, t = oi - o * LOUT;
        float acc = conv_b[o];
        const float* wp = conv_w + o * (Hd * KW);
        for (int ci = 0; ci < Hd; ++ci) {
#pragma unroll
            for (int k = 0; k < KW; ++k)
                acc = fmaf(xc[t + k][ci], wp[ci * KW + k], acc);
        }
        flat[oi] = fmaxf(acc, 0.f);
    }
    __syncthreads();
    if (tid < Hd) {
        float acc = l1b[tid];
        for (int m = 0; m < CO * LOUT; ++m)
            acc = fmaf(flat[m], l1w[m * Hd + tid], acc);
        z[tid] = fmaxf(acc, 0.f);
    }
    __syncthreads();
    if (tid < 10) {
        float acc = l2b[tid];
        for (int j = 0; j < Hd; ++j)
            acc = fmaf(z[j], l2w[j * 10 + tid], acc);
        out[b * 10 + tid] = acc;
    }
}

extern "C" void kernel_launch(void* const* d_in, const int* in_sizes, int n_in,
                              void* d_out, int out_size, void* d_ws, size_t ws_size,
                              hipStream_t stream) {
    const float* x      = (const float*)d_in[0];
    const int*   ei     = (const int*)d_in[1];
    const int*   batch  = (const int*)d_in[2];
    const float* W0     = (const float*)d_in[3];
    const float* b0     = (const float*)d_in[4];
    const float* W1     = (const float*)d_in[5];
    const float* b1     = (const float*)d_in[6];
    const float* W2     = (const float*)d_in[7];
    const float* b2     = (const float*)d_in[8];
    const float* conv_w = (const float*)d_in[9];
    const float* conv_b = (const float*)d_in[10];
    const float* l1w    = (const float*)d_in[11];
    const float* l1b    = (const float*)d_in[12];
    const float* l2w    = (const float*)d_in[13];
    const float* l2b    = (const float*)d_in[14];
    float* out = (float*)d_out;

    // workspace layout (ints/floats are 4B; hw/hbuf kept 16B aligned)
    int* wsI = (int*)d_ws;
    size_t off = 0;
    int*   deg_i   = wsI + off; off += Nn;
    int*   cnt     = wsI + off; off += Nn;
    int*   row_ptr = wsI + off; off += 50004;      // N+1 padded
    int*   bstart  = wsI + off; off += 132;        // B+1 padded
    float* dinv    = (float*)(wsI + off); off += Nn;
    int*   sel     = wsI + off; off += Bg * Kt + 16;
    int*   bsum    = wsI + off; off += 256;
    int*   boff    = wsI + off; off += 256;
    int*   csr_src = wsI + off; off += Ee;
    // align to 16B
    off = (off + 3) & ~(size_t)3;
    float* hw   = (float*)(wsI + off); off += (size_t)Nn * Hd;
    float* hbuf = (float*)(wsI + off); off += (size_t)Nn * Hd;

    // 1. init
    init_kernel<<<(Nn + 255) / 256, 256, 0, stream>>>(deg_i, cnt, bstart);
    // 2. degree histogram + batch starts (boundary detect)
    count_kernel<<<(Ee + 255) / 256, 256, 0, stream>>>(ei, batch, deg_i, bstart);
    // 3. multi-block exclusive scan -> row_ptr, dinv; fix bstart
    scanA_kernel<<<SCB, 256, 0, stream>>>(deg_i, dinv, bsum);
    scanB_kernel<<<1, 256, 0, stream>>>(bsum, boff, bstart);
    scanC_kernel<<<SCB, 256, 0, stream>>>(deg_i, boff, row_ptr);
    // 4. CSR fill
    fill_kernel<<<(Ee + 255) / 256, 256, 0, stream>>>(ei, row_ptr, cnt, csr_src);

    // 5. three GCN layers
    dim3 mmGrid((Nn + MMR - 1) / MMR);
    dim3 aggGrid((Nn + 3) / 4);
    mm_kernel<<<mmGrid, 256, 0, stream>>>(x, W0, dinv, hw);
    agg_kernel<<<aggGrid, 256, 0, stream>>>(hw, row_ptr, csr_src, dinv, b0, hbuf);
    mm_kernel<<<mmGrid, 256, 0, stream>>>(hbuf, W1, dinv, hw);
    agg_kernel<<<aggGrid, 256, 0, stream>>>(hw, row_ptr, csr_src, dinv, b1, hbuf);
    mm_kernel<<<mmGrid, 256, 0, stream>>>(hbuf, W2, dinv, hw);
    agg_kernel<<<aggGrid, 256, 0, stream>>>(hw, row_ptr, csr_src, dinv, b2, hbuf);

    // 6. sort-pool top-K per batch
    topk_kernel<<<Bg, 256, 0, stream>>>(hbuf, bstart, sel);
    // 7. fused conv + fc head
    head_kernel<<<Bg, 256, 0, stream>>>(hbuf, sel, conv_w, conv_b, l1w, l1b, l2w, l2b, out);
}

// Round 4
// 492.468 us; speedup vs baseline: 1.5300x; 1.0690x over previous
//
#include <hip/hip_runtime.h>
#include <math.h>

#define Nn 50000
#define Ee 600000
#define Bg 128      // batches (graphs)
#define Hd 128      // hidden dim
#define Kt 30       // sortpool K
#define CO 32       // conv out channels
#define KW 5        // conv kernel
#define LOUT 26     // K - KW + 1
#define CAP 2048    // per-batch node cap for topk LDS (max real count ~460)
#define SCB 196     // ceil(50000/256) scan blocks
#define CVO 8       // conv o's per block (grid y = CO/CVO = 4)

// ---------------- init ----------------
__global__ void init_kernel(int* __restrict__ deg_i, int* __restrict__ cnt,
                            int* __restrict__ bstart) {
    int i = blockIdx.x * 256 + threadIdx.x;
    if (i < Nn) { deg_i[i] = 1; cnt[i] = 0; }   // deg starts at 1 (self loop)
    if (i <= Bg) bstart[i] = Nn;                // sentinel
}

// ---------------- degree histogram + batch starts (boundary detect) ----------
__global__ void count_kernel(const int* __restrict__ ei, const int* __restrict__ batch,
                             int* __restrict__ deg_i, int* __restrict__ bstart) {
    int i = blockIdx.x * 256 + threadIdx.x;
    if (i < Ee) atomicAdd(&deg_i[ei[Ee + i]], 1);       // col = edge_index[1]
    if (i < Nn) {
        int b = batch[i];
        if (i == 0) {
            bstart[b] = 0;
        } else {
            int bp = batch[i - 1];
            if (bp != b) bstart[b] = i;
        }
    }
}

// ---------------- scan phase A: block sums of (deg-1), dinv ----------------
__global__ __launch_bounds__(256) void scanA_kernel(const int* __restrict__ deg_i,
                            float* __restrict__ dinv, int* __restrict__ bsum) {
    __shared__ int s[256];
    int tid = threadIdx.x;
    int i = blockIdx.x * 256 + tid;
    int v = 0;
    if (i < Nn) {
        int d = deg_i[i];
        dinv[i] = 1.0f / sqrtf((float)d);
        v = d - 1;
    }
    s[tid] = v;
    __syncthreads();
    for (int off = 128; off > 0; off >>= 1) {
        if (tid < off) s[tid] += s[tid + off];
        __syncthreads();
    }
    if (tid == 0) bsum[blockIdx.x] = s[0];
}

// ---------------- scan phase B: scan block sums; fix empty batches ----------
__global__ __launch_bounds__(256) void scanB_kernel(const int* __restrict__ bsum,
                            int* __restrict__ boff, int* __restrict__ bstart) {
    __shared__ int s[256];
    int tid = threadIdx.x;
    int v = (tid < SCB) ? bsum[tid] : 0;
    s[tid] = v;
    __syncthreads();
    for (int off = 1; off < 256; off <<= 1) {
        int t = (tid >= off) ? s[tid - off] : 0;
        __syncthreads();
        s[tid] += t;
        __syncthreads();
    }
    if (tid < SCB) boff[tid] = s[tid] - v;   // exclusive
    if (tid == 0) {   // empty batches inherit next start (batch array sorted)
        for (int b = Bg - 1; b >= 0; --b)
            if (bstart[b] == Nn) bstart[b] = bstart[b + 1];
    }
}

// ---------------- scan phase C: row_ptr = offset + local inclusive scan -----
__global__ __launch_bounds__(256) void scanC_kernel(const int* __restrict__ deg_i,
                            const int* __restrict__ boff, int* __restrict__ row_ptr) {
    __shared__ int s[256];
    int tid = threadIdx.x;
    int i = blockIdx.x * 256 + tid;
    int v = (i < Nn) ? deg_i[i] - 1 : 0;
    s[tid] = v;
    __syncthreads();
    for (int off = 1; off < 256; off <<= 1) {
        int t = (tid >= off) ? s[tid - off] : 0;
        __syncthreads();
        s[tid] += t;
        __syncthreads();
    }
    if (i < Nn) row_ptr[i + 1] = s[tid] + boff[blockIdx.x];
    if (i == 0) row_ptr[0] = 0;
}

// ---------------- CSR fill (edges grouped by destination col) ----------------
__global__ void fill_kernel(const int* __restrict__ ei, const int* __restrict__ row_ptr,
                            int* __restrict__ cnt, int* __restrict__ csr_src) {
    int e = blockIdx.x * 256 + threadIdx.x;
    if (e >= Ee) return;
    int c = ei[Ee + e];
    int r = ei[e];
    int p = row_ptr[c] + atomicAdd(&cnt[c], 1);
    csr_src[p] = r;
}

// ---------------- matmul: hw[i] = dinv[i] * (Hin[i] @ W) ----------------
#define MMR 64
__global__ __launch_bounds__(256) void mm_kernel(const float* __restrict__ Hin,
                            const float* __restrict__ W, const float* __restrict__ dinv,
                            float* __restrict__ hw) {
    __shared__ float hl[MMR * Hd];
    int row0 = blockIdx.x * MMR;
    int tid = threadIdx.x;
    for (int i = tid; i < MMR * Hd / 4; i += 256) {
        int r = i >> 5;
        int gr = row0 + r;
        float4 v = make_float4(0.f, 0.f, 0.f, 0.f);
        if (gr < Nn) v = ((const float4*)(Hin + (size_t)gr * Hd))[i & 31];
        ((float4*)hl)[i] = v;
    }
    __syncthreads();
    int cg = tid & 31;
    int rg = tid >> 5;
    float acc[8][4];
#pragma unroll
    for (int i = 0; i < 8; ++i)
#pragma unroll
        for (int j = 0; j < 4; ++j) acc[i][j] = 0.f;

    const float* hb = hl + rg * 8 * Hd;
#pragma unroll 4
    for (int k = 0; k < Hd; ++k) {
        float4 w = *(const float4*)(W + k * Hd + cg * 4);
#pragma unroll
        for (int i = 0; i < 8; ++i) {
            float hv = hb[i * Hd + k];
            acc[i][0] = fmaf(hv, w.x, acc[i][0]);
            acc[i][1] = fmaf(hv, w.y, acc[i][1]);
            acc[i][2] = fmaf(hv, w.z, acc[i][2]);
            acc[i][3] = fmaf(hv, w.w, acc[i][3]);
        }
    }
#pragma unroll
    for (int i = 0; i < 8; ++i) {
        int r = row0 + rg * 8 + i;
        if (r < Nn) {
            float s = dinv[r];
            float4 o = make_float4(acc[i][0] * s, acc[i][1] * s, acc[i][2] * s, acc[i][3] * s);
            *(float4*)(hw + (size_t)r * Hd + cg * 4) = o;
        }
    }
}

// ---------------- aggregation: h[i] = relu(dinv[i]*(hw[i] + sum_src hw[src]) + b) ----
__global__ __launch_bounds__(256) void agg_kernel(const float* __restrict__ hw,
                            const int* __restrict__ row_ptr, const int* __restrict__ csr_src,
                            const float* __restrict__ dinv, const float* __restrict__ bias,
                            float* __restrict__ hout) {
    int node = blockIdx.x * 4 + (threadIdx.x >> 6);
    if (node >= Nn) return;
    int lane = threadIdx.x & 63;
    const float2* hw2 = (const float2*)hw;
    float2 acc = hw2[(size_t)node * 64 + lane];
    int e0 = row_ptr[node], e1 = row_ptr[node + 1];
    int e = e0;
    for (; e + 1 < e1; e += 2) {
        int s0 = csr_src[e], s1 = csr_src[e + 1];
        float2 v0 = hw2[(size_t)s0 * 64 + lane];
        float2 v1 = hw2[(size_t)s1 * 64 + lane];
        acc.x += v0.x + v1.x;
        acc.y += v0.y + v1.y;
    }
    if (e < e1) {
        int s0 = csr_src[e];
        float2 v0 = hw2[(size_t)s0 * 64 + lane];
        acc.x += v0.x;
        acc.y += v0.y;
    }
    float d = dinv[node];
    float2 bv = ((const float2*)bias)[lane];
    float2 o;
    o.x = fmaxf(fmaf(d, acc.x, bv.x), 0.f);
    o.y = fmaxf(fmaf(d, acc.y, bv.y), 0.f);
    ((float2*)hout)[(size_t)node * 64 + lane] = o;
}

// ---------------- top-K per batch + gather pooled tile to xcg ----------------
__global__ __launch_bounds__(256) void topk_kernel(const float* __restrict__ h,
                            const int* __restrict__ bstart, float* __restrict__ xcg) {
    __shared__ float vals[CAP];
    __shared__ float rv[4];
    __shared__ int ri[4];
    __shared__ int selS[Kt];
    int b = blockIdx.x, tid = threadIdx.x;
    int s0 = bstart[b], s1 = bstart[b + 1];
    int n = s1 - s0;
    int nc = n < CAP ? n : CAP;
    for (int j = tid; j < nc; j += 256)
        vals[j] = h[(size_t)(s0 + j) * Hd + (Hd - 1)];
    __syncthreads();
    for (int k = 0; k < Kt; ++k) {
        float bv = -1.f;
        int bi = 0x7fffffff;
        for (int j = tid; j < nc; j += 256) {
            float v = vals[j];
            if (v > bv || (v == bv && j < bi)) { bv = v; bi = j; }
        }
        for (int off = 32; off > 0; off >>= 1) {
            float ov = __shfl_down(bv, off);
            int oi = __shfl_down(bi, off);
            if (ov > bv || (ov == bv && oi < bi)) { bv = ov; bi = oi; }
        }
        int wid = tid >> 6;
        if ((tid & 63) == 0) { rv[wid] = bv; ri[wid] = bi; }
        __syncthreads();
        if (tid == 0) {
            float fv = rv[0]; int fi = ri[0];
            for (int w = 1; w < 4; ++w) {
                if (rv[w] > fv || (rv[w] == fv && ri[w] < fi)) { fv = rv[w]; fi = ri[w]; }
            }
            if (k < n) {
                selS[k] = s0 + fi;
                vals[fi] = -1.f;   // relu output >= 0, so -1 can never win again
            } else {
                selS[k] = -1;
            }
        }
        __syncthreads();
    }
    // gather pooled tile: xcg[b][t][c]
    for (int i = tid; i < Kt * Hd; i += 256) {
        int t = i >> 7, c = i & 127;
        int s = selS[t];
        xcg[((size_t)b * Kt + t) * Hd + c] = (s >= 0) ? h[(size_t)s * Hd + c] : 0.f;
    }
}

// ---------------- conv_w transpose: wT2[o][k][ci] = conv_w[o][ci][k] ---------
__global__ void wtr_kernel(const float* __restrict__ conv_w, float* __restrict__ wT2) {
    int i = blockIdx.x * 256 + threadIdx.x;
    if (i >= CO * KW * Hd) return;
    int ci = i & 127;
    int r = i >> 7;          // o*KW + k
    int o = r / KW, k = r - o * KW;
    wT2[i] = conv_w[((size_t)o * Hd + ci) * KW + k];
}

// ---------------- conv: flatg[b][o][t] = relu(conv_b[o] + xc . w) -----------
// grid (Bg, CO/CVO); xc slice in LDS (row stride 130 -> float2 2-way bank alias = free),
// wT2 from global (L1 broadcast across the 26-lane t-groups)
__global__ __launch_bounds__(256) void conv_kernel(const float* __restrict__ xcg,
                            const float* __restrict__ wT2, const float* __restrict__ conv_b,
                            float* __restrict__ flatg) {
    __shared__ float xcl[Kt][130];
    int b = blockIdx.x, q = blockIdx.y;
    int o0 = q * CVO;
    int tid = threadIdx.x;
    for (int i = tid; i < Kt * 32; i += 256) {   // 960 float4
        int t = i >> 5, c4 = i & 31;
        float4 v = ((const float4*)(xcg + ((size_t)b * Kt + t) * Hd))[c4];
        float2* dst = (float2*)&xcl[t][c4 * 4];
        dst[0] = make_float2(v.x, v.y);
        dst[1] = make_float2(v.z, v.w);
    }
    __syncthreads();
    int idx = tid;
    if (idx < CVO * LOUT) {
        int op = idx / LOUT, t = idx - op * LOUT;
        int o = o0 + op;
        float acc = conv_b[o];
#pragma unroll
        for (int k = 0; k < KW; ++k) {
            const float* xr = &xcl[t + k][0];
            const float* wr = wT2 + ((size_t)o * KW + k) * Hd;
#pragma unroll 8
            for (int c4 = 0; c4 < 32; ++c4) {
                float2 xa = *(const float2*)(xr + c4 * 4);
                float2 xb = *(const float2*)(xr + c4 * 4 + 2);
                float4 wv = *(const float4*)(wr + c4 * 4);
                acc = fmaf(xa.x, wv.x, acc);
                acc = fmaf(xa.y, wv.y, acc);
                acc = fmaf(xb.x, wv.z, acc);
                acc = fmaf(xb.y, wv.w, acc);
            }
        }
        flatg[((size_t)b * CO + o) * LOUT + t] = fmaxf(acc, 0.f);
    }
}

// ---------------- lin1 partials: pz[b][q8][h] over m-chunks of 104 ----------
__global__ __launch_bounds__(256) void lin1_kernel(const float* __restrict__ flatg,
                            const float* __restrict__ l1w, float* __restrict__ pz) {
    int b = blockIdx.x, mq = blockIdx.y;    // grid (Bg, 4)
    int tid = threadIdx.x;
    int hh = tid & 127, half = tid >> 7;
    int m0 = mq * 208 + half * 104;
    const float* fp = flatg + (size_t)b * (CO * LOUT) + m0;
    const float* wp = l1w + (size_t)m0 * Hd + hh;
    float acc = 0.f;
#pragma unroll 8
    for (int m = 0; m < 104; ++m)
        acc = fmaf(fp[m], wp[(size_t)m * Hd], acc);
    pz[((size_t)b * 8 + mq * 2 + half) * Hd + hh] = acc;
}

// ---------------- head finish: z = relu(sum pz + b1); out = z@l2w + b2 ------
__global__ __launch_bounds__(128) void headfin_kernel(const float* __restrict__ pz,
                            const float* __restrict__ l1b, const float* __restrict__ l2w,
                            const float* __restrict__ l2b, float* __restrict__ out) {
    __shared__ float z[Hd];
    int b = blockIdx.x, tid = threadIdx.x;
    float acc = l1b[tid];
#pragma unroll
    for (int q = 0; q < 8; ++q)
        acc += pz[((size_t)b * 8 + q) * Hd + tid];
    z[tid] = fmaxf(acc, 0.f);
    __syncthreads();
    if (tid < 10) {
        float a2 = l2b[tid];
        for (int j = 0; j < Hd; ++j)
            a2 = fmaf(z[j], l2w[j * 10 + tid], a2);
        out[b * 10 + tid] = a2;
    }
}

extern "C" void kernel_launch(void* const* d_in, const int* in_sizes, int n_in,
                              void* d_out, int out_size, void* d_ws, size_t ws_size,
                              hipStream_t stream) {
    const float* x      = (const float*)d_in[0];
    const int*   ei     = (const int*)d_in[1];
    const int*   batch  = (const int*)d_in[2];
    const float* W0     = (const float*)d_in[3];
    const float* b0     = (const float*)d_in[4];
    const float* W1     = (const float*)d_in[5];
    const float* b1     = (const float*)d_in[6];
    const float* W2     = (const float*)d_in[7];
    const float* b2     = (const float*)d_in[8];
    const float* conv_w = (const float*)d_in[9];
    const float* conv_b = (const float*)d_in[10];
    const float* l1w    = (const float*)d_in[11];
    const float* l1b    = (const float*)d_in[12];
    const float* l2w    = (const float*)d_in[13];
    const float* l2b    = (const float*)d_in[14];
    float* out = (float*)d_out;

    // workspace layout
    int* wsI = (int*)d_ws;
    size_t off = 0;
    int*   deg_i   = wsI + off; off += Nn;
    int*   cnt     = wsI + off; off += Nn;
    int*   row_ptr = wsI + off; off += 50004;
    int*   bstart  = wsI + off; off += 132;
    float* dinv    = (float*)(wsI + off); off += Nn;
    int*   bsum    = wsI + off; off += 256;
    int*   boff    = wsI + off; off += 256;
    int*   csr_src = wsI + off; off += Ee;
    off = (off + 3) & ~(size_t)3;        // 16B align
    float* hw    = (float*)(wsI + off); off += (size_t)Nn * Hd;
    float* hbuf  = (float*)(wsI + off); off += (size_t)Nn * Hd;
    float* xcg   = (float*)(wsI + off); off += (size_t)Bg * Kt * Hd;
    float* wT2   = (float*)(wsI + off); off += CO * KW * Hd;
    float* flatg = (float*)(wsI + off); off += (size_t)Bg * CO * LOUT;
    float* pz    = (float*)(wsI + off); off += (size_t)Bg * 8 * Hd;

    // 1. init
    init_kernel<<<(Nn + 255) / 256, 256, 0, stream>>>(deg_i, cnt, bstart);
    // 2. degree histogram + batch starts
    count_kernel<<<(Ee + 255) / 256, 256, 0, stream>>>(ei, batch, deg_i, bstart);
    // conv_w transpose (independent; cheap)
    wtr_kernel<<<(CO * KW * Hd + 255) / 256, 256, 0, stream>>>(conv_w, wT2);
    // 3. multi-block exclusive scan -> row_ptr, dinv; fix bstart
    scanA_kernel<<<SCB, 256, 0, stream>>>(deg_i, dinv, bsum);
    scanB_kernel<<<1, 256, 0, stream>>>(bsum, boff, bstart);
    scanC_kernel<<<SCB, 256, 0, stream>>>(deg_i, boff, row_ptr);
    // 4. CSR fill
    fill_kernel<<<(Ee + 255) / 256, 256, 0, stream>>>(ei, row_ptr, cnt, csr_src);

    // 5. three GCN layers
    dim3 mmGrid((Nn + MMR - 1) / MMR);
    dim3 aggGrid((Nn + 3) / 4);
    mm_kernel<<<mmGrid, 256, 0, stream>>>(x, W0, dinv, hw);
    agg_kernel<<<aggGrid, 256, 0, stream>>>(hw, row_ptr, csr_src, dinv, b0, hbuf);
    mm_kernel<<<mmGrid, 256, 0, stream>>>(hbuf, W1, dinv, hw);
    agg_kernel<<<aggGrid, 256, 0, stream>>>(hw, row_ptr, csr_src, dinv, b1, hbuf);
    mm_kernel<<<mmGrid, 256, 0, stream>>>(hbuf, W2, dinv, hw);
    agg_kernel<<<aggGrid, 256, 0, stream>>>(hw, row_ptr, csr_src, dinv, b2, hbuf);

    // 6. sort-pool top-K + gather
    topk_kernel<<<Bg, 256, 0, stream>>>(hbuf, bstart, xcg);
    // 7. head pipeline: conv -> lin1 partials -> finish
    conv_kernel<<<dim3(Bg, CO / CVO), 256, 0, stream>>>(xcg, wT2, conv_b, flatg);
    lin1_kernel<<<dim3(Bg, 4), 256, 0, stream>>>(flatg, l1w, pz);
    headfin_kernel<<<Bg, 128, 0, stream>>>(pz, l1b, l2w, l2b, out);
}